// Round 5
// baseline (487.860 us; speedup 1.0000x reference)
//
#include <hip/hip_runtime.h>

// ---------------------------------------------------------------------------
// ZSSR involution net, fp32. Round 20 = R16 body (8x8 tile, 5 WG/CU, best
// per-layer config at 175.3us) + cooperative 6-layer fusion with a TWO-LEVEL
// TREE barrier (R18's single-counter barrier cost ~64us/sync = 1184 serial
// RMWs; tree: 37 groups x 32 WGs -> ~32+37 serial RMWs ~ 5us/sync).
// Monotonic counters (no reset): group-last arriver (prev == target*32-1)
// RMWs root; root-last (prev == target*37-1) release-stores gen = target.
// R19's 16x8 tile regressed (3 WG/CU killed latency hiding) - reverted.
// conv_in zeroes the 39 barrier words. Fallback: 6-dispatch path (R16 perf).
// Layout: x[4 g][136x136 px][16 ch] channel-last, 3-px zero border.
// ---------------------------------------------------------------------------

#define HH 130
#define SP 136               // padded row stride
#define PPL (SP*SP)          // 18496
#define GP (PPL*16)          // floats per group-plane
#define XBUF2 (4*GP)         // floats per feature buffer
#define TP1 (16900*16)       // one group-partial buffer [px][16]
#define OFF_TA (2*XBUF2)             // set A: 4 buffers
#define OFF_TB (OFF_TA + 4*TP1)      // set B: 4 buffers
#define OFF_BAR (OFF_TB + 4*TP1)     // barrier words: grp[37],root,gen @128B

#define NGRP 37

// --- two-level tree grid barrier (monotonic counters) ----------------------
__device__ __forceinline__ void grid_bar(unsigned* bar, unsigned target,
                                         int wid) {
    __syncthreads();                   // drains vmem per wave
    if (threadIdx.x == 0) {
        unsigned* grp  = bar + (wid >> 5)*32;   // 37 groups of 32 WGs
        unsigned* root = bar + NGRP*32;
        unsigned* gen  = bar + (NGRP+1)*32;
        unsigned prev = __hip_atomic_fetch_add(grp, 1u, __ATOMIC_ACQ_REL,
                                               __HIP_MEMORY_SCOPE_AGENT);
        if (prev == target*32u - 1u) {          // last in group this round
            unsigned prev2 = __hip_atomic_fetch_add(root, 1u,
                                                    __ATOMIC_ACQ_REL,
                                                    __HIP_MEMORY_SCOPE_AGENT);
            if (prev2 == target*(unsigned)NGRP - 1u) {
                __hip_atomic_store(gen, target, __ATOMIC_RELEASE,
                                   __HIP_MEMORY_SCOPE_AGENT);
            } else {
                while (__hip_atomic_load(gen, __ATOMIC_RELAXED,
                                         __HIP_MEMORY_SCOPE_AGENT) < target)
                    __builtin_amdgcn_s_sleep(2);
                (void)__hip_atomic_load(gen, __ATOMIC_ACQUIRE,
                                        __HIP_MEMORY_SCOPE_AGENT);
            }
        } else {
            while (__hip_atomic_load(gen, __ATOMIC_RELAXED,
                                     __HIP_MEMORY_SCOPE_AGENT) < target)
                __builtin_amdgcn_s_sleep(2);
            (void)__hip_atomic_load(gen, __ATOMIC_ACQUIRE,
                                    __HIP_MEMORY_SCOPE_AGENT);
        }
    }
    __syncthreads();
}

// --- conv_in (3->64, 3x3, pad=2) + border zeroing + layer-0 t partials -----
__global__ __launch_bounds__(256) void conv_in_kernel(
        const float* __restrict__ inf, const float* __restrict__ W,
        const float* __restrict__ b, float* __restrict__ x0,
        float* __restrict__ x1, float* __restrict__ tpA,
        const float* __restrict__ redw0,     // [16][64] layer 0
        unsigned* __restrict__ bar) {        // barrier words to zero
    const int tid = threadIdx.x;
    if (blockIdx.x >= 67) {
        if (blockIdx.x == 79 && blockIdx.y == 3 && tid < NGRP + 2)
            bar[tid*32] = 0u;            // 37 grp + root + gen
        int idx = ((blockIdx.x - 67)*4 + blockIdx.y)*256 + tid;
        if (idx < 3192) {                      // 1596 border px * 2 buffers
            int bsel = idx & 1, e = idx >> 1;
            int r, c;
            if (e < 816) { r = e/136; c = e%136; if (r >= 3) r += 130; }
            else { int j = e-816; r = 3 + j/6; int m = j%6; c = (m<3)? m : m+130; }
            float* base = (bsel ? x1 : x0) + ((size_t)r*SP + c)*16;
            float4 z = make_float4(0.f,0.f,0.f,0.f);
            #pragma unroll
            for (int g2 = 0; g2 < 4; ++g2)
                #pragma unroll
                for (int q = 0; q < 4; ++q)
                    *(float4*)(base + (size_t)g2*GP + q*4) = z;
        }
        return;
    }
    __shared__ float wl[448];          // [16 ch][27 taps] + bias[16]
    const int g = blockIdx.y;
    for (int i = tid; i < 448; i += 256)
        wl[i] = (i < 432) ? W[g*432 + i] : b[g*16 + (i-432)];
    __syncthreads();
    int px = blockIdx.x*256 + tid;
    int pxc = px < 16900 ? px : 16899;
    int h = pxc/130, w = pxc%130;
    float xv[27];
    #pragma unroll
    for (int i = 0; i < 3; ++i)
      #pragma unroll
      for (int ky = 0; ky < 3; ++ky) {
        int y = h - 2 + ky;
        #pragma unroll
        for (int kx = 0; kx < 3; ++kx) {
            int xx = w - 2 + kx;
            float v = 0.f;
            if ((unsigned)y < 128u && (unsigned)xx < 128u)
                v = inf[i*16384 + y*128 + xx];
            xv[i*9 + ky*3 + kx] = v;
        }
      }
    float acc[16];
    #pragma unroll
    for (int c = 0; c < 16; ++c) {
        float a = wl[432 + c];
        #pragma unroll
        for (int t = 0; t < 27; ++t) a += wl[c*27 + t] * xv[t];
        acc[c] = a;
    }
    if (px < 16900) {
        float* dst = x0 + (size_t)g*GP + ((size_t)(h+3)*SP + (w+3))*16;
        #pragma unroll
        for (int q = 0; q < 4; ++q)
            *(float4*)(dst + q*4) =
                make_float4(acc[q*4], acc[q*4+1], acc[q*4+2], acc[q*4+3]);
        // layer-0 t partial for group g (thread owns all 16 ch; s_load redw0)
        float* td = tpA + (size_t)g*TP1 + (size_t)px*16;
        #pragma unroll
        for (int rq = 0; rq < 4; ++rq) {
            float p0=0.f, p1=0.f, p2=0.f, p3=0.f;
            #pragma unroll
            for (int j = 0; j < 16; ++j) {
                float a = acc[j];
                p0 += redw0[(rq*4+0)*64 + g*16 + j]*a;
                p1 += redw0[(rq*4+1)*64 + g*16 + j]*a;
                p2 += redw0[(rq*4+2)*64 + g*16 + j]*a;
                p3 += redw0[(rq*4+3)*64 + g*16 + j]*a;
            }
            *(float4*)(td + rq*4) = make_float4(p0, p1, p2, p3);
        }
    }
}

// ---------------------------------------------------------------------------
// Shared layer body (R16 e_kernel v12, the 175.3us config).
// grid 1184: wid&7 = band, slot = wid>>3; T = band*37+(slot>>2), g = slot&3.
// LDS: xl[4][14][17][4] 15232B + uu (tl[64][20] ALIAS wl[49][68]) 13328B
//    = 28560B -> 5 WG/CU at launch_bounds(256,5).
#define TL(p, r)  uu[(p)*20 + (r)]
#define WLK(k, p) uu[(k)*68 + (p)]

__device__ __forceinline__ void inv_layer_body(
        float (*xl)[14][17][4], float* uu,
        const int T, const int g, const int ty, const int tx,
        const int tid, const int px, const int wv, const int sr, const int sc,
        const float* __restrict__ x,
        const float* __restrict__ tread,
        float* __restrict__ twrite,
        const float* __restrict__ gamma, const float* __restrict__ beta,
        const float* __restrict__ spanw, const float* __restrict__ spanb,
        const float* __restrict__ redwn,
        float* __restrict__ xout,
        const int doNext)
{
    // ---- stage halo: 14x14 px, 4 quads (group g's 16 ch) ----
    for (int i = tid; i < 784; i += 256) {
        int q = i & 3, p = i >> 2;
        int r = p / 14, c = p % 14;
        int gr = ty + r, gc = tx + c;
        gr = gr < SP ? gr : SP-1;          // clamp lands in zero border
        gc = gc < SP ? gc : SP-1;
        float4 v = *(const float4*)(x + (size_t)g*GP
                                    + ((size_t)gr*SP + gc)*16 + q*4);
        *(float4*)&xl[q][r][c][0] = v;
    }

    // ---- t dedup: thread (px,wv) sums r-quad wv across the 4 partials ----
    const int hh = min(ty + sr, HH-1), ww = min(tx + sc, HH-1);
    {
        const size_t toff = ((size_t)hh*HH + ww)*16 + wv*4;
        float4 s = make_float4(0.f,0.f,0.f,0.f);
        #pragma unroll
        for (int gg = 0; gg < 4; ++gg) {
            float4 a = *(const float4*)(tread + (size_t)gg*TP1 + toff);
            s.x += a.x; s.y += a.y; s.z += a.z; s.w += a.w;
        }
        *(float4*)&TL(px, wv*4) = s;       // raw sums (BN applied on read)
    }
    __syncthreads();                       // #1: tl complete

    // ---- read t16 (BN+ReLU) ----
    float t16[16];
    #pragma unroll
    for (int q = 0; q < 4; ++q) {
        float4 v = *(const float4*)&TL(px, q*4);
        t16[q*4+0] = fmaxf(gamma[q*4+0]*v.x + beta[q*4+0], 0.f);
        t16[q*4+1] = fmaxf(gamma[q*4+1]*v.y + beta[q*4+1], 0.f);
        t16[q*4+2] = fmaxf(gamma[q*4+2]*v.z + beta[q*4+2], 0.f);
        t16[q*4+3] = fmaxf(gamma[q*4+3]*v.w + beta[q*4+3], 0.f);
    }
    __syncthreads();                       // #2: tl reads done, wl may write

    // ---- w-gen: lane = pixel, wave = k-chunk (13/12/12/12) ----
    {
        const float* sw = spanw + g*784;   // k,r wave-uniform -> s_load
        const float* sb = spanb + g*49;
        const int k0 = wv ? (wv*12 + 1) : 0;
        #pragma unroll
        for (int j = 0; j < 12; ++j) {
            int k = k0 + j;
            float a = sb[k];
            #pragma unroll
            for (int r = 0; r < 16; ++r) a += sw[k*16 + r] * t16[r];
            WLK(k, px) = a;
        }
        if (wv == 0) {
            float a = sb[12];
            #pragma unroll
            for (int r = 0; r < 16; ++r) a += sw[12*16 + r] * t16[r];
            WLK(12, px) = a;
        }
    }
    __syncthreads();                       // #3: wl complete (and halo in xl)

    // ---- einsum: 1x2 px register blocking, waves 0-1 only ----
    float4 o0 = make_float4(0.f,0.f,0.f,0.f);
    float4 o1 = make_float4(0.f,0.f,0.f,0.f);
    int px0 = 0, cq2 = 0;
    if (tid < 128) {
        cq2 = tid >> 5;                    // 0..3 (wave0: 0,1; wave1: 2,3)
        const int pr = tid & 31;
        const int sr2 = pr >> 2, sc0 = (pr & 3)*2;
        px0 = sr2*8 + sc0;
        float4 a0 = make_float4(0.f,0.f,0.f,0.f);
        float4 a1 = make_float4(0.f,0.f,0.f,0.f);
        #pragma unroll
        for (int i = 0; i < 7; ++i) {
            float4 row[8];
            #pragma unroll
            for (int j = 0; j < 8; ++j)
                row[j] = *(const float4*)&xl[cq2][sr2 + i][sc0 + j][0];
            #pragma unroll
            for (int j = 0; j < 7; ++j) {
                float2 wp = *(const float2*)&WLK(i*7 + j, px0);
                a0.x += wp.x*row[j].x;   a0.y += wp.x*row[j].y;
                a0.z += wp.x*row[j].z;   a0.w += wp.x*row[j].w;
                a1.x += wp.y*row[j+1].x; a1.y += wp.y*row[j+1].y;
                a1.z += wp.y*row[j+1].z; a1.w += wp.y*row[j+1].w;
            }
        }
        o0 = make_float4(fmaxf(a0.x,0.f), fmaxf(a0.y,0.f),
                         fmaxf(a0.z,0.f), fmaxf(a0.w,0.f));
        o1 = make_float4(fmaxf(a1.x,0.f), fmaxf(a1.y,0.f),
                         fmaxf(a1.z,0.f), fmaxf(a1.w,0.f));
        const int h2 = ty + sr2, w2 = tx + sc0;
        if (h2 < HH) {
            float* ob = xout + (size_t)g*GP
                        + ((size_t)(h2+3)*SP + (w2+3))*16 + cq2*4;
            if (w2 < HH)     *(float4*)ob        = o0;
            if (w2+1 < HH)   *(float4*)(ob + 16) = o1;
        }
    }

    // ---- next-layer t partial: in-WG reduce via dead xl, plain stores -----
    if (doNext) {
        float* ol = (float*)xl;            // [64][17], 2-way banks
        __syncthreads();                   // einsum reads of xl done
        if (tid < 128) {
            ol[ px0   *17 + cq2*4 + 0] = o0.x;
            ol[ px0   *17 + cq2*4 + 1] = o0.y;
            ol[ px0   *17 + cq2*4 + 2] = o0.z;
            ol[ px0   *17 + cq2*4 + 3] = o0.w;
            ol[(px0+1)*17 + cq2*4 + 0] = o1.x;
            ol[(px0+1)*17 + cq2*4 + 1] = o1.y;
            ol[(px0+1)*17 + cq2*4 + 2] = o1.z;
            ol[(px0+1)*17 + cq2*4 + 3] = o1.w;
        }
        __syncthreads();
        // thread (px, rq = wv): partial t rows rq*4..+3 over group's 16 ch
        const int rq = wv;
        float p0=0.f, p1=0.f, p2=0.f, p3=0.f;
        #pragma unroll
        for (int j = 0; j < 16; ++j) {
            float xv = ol[px*17 + j];
            const int c = g*16 + j;        // wave-uniform -> s_load redwn
            p0 += redwn[(rq*4+0)*64 + c]*xv;
            p1 += redwn[(rq*4+1)*64 + c]*xv;
            p2 += redwn[(rq*4+2)*64 + c]*xv;
            p3 += redwn[(rq*4+3)*64 + c]*xv;
        }
        const int hR = ty + sr, wR = tx + sc;
        if (hR < HH && wR < HH)
            *(float4*)(twrite + (size_t)g*TP1
                       + ((size_t)hR*HH + wR)*16 + rq*4) =
                make_float4(p0, p1, p2, p3);
    }
}

// --- fused 6-layer cooperative kernel with tree barrier --------------------
__global__ __launch_bounds__(256, 5) void inv_all_kernel(
        float* __restrict__ x0buf, float* __restrict__ x1buf,
        float* __restrict__ tAbuf, float* __restrict__ tBbuf,
        const float* __restrict__ gam, const float* __restrict__ bet,
        const float* __restrict__ spw, const float* __restrict__ spb,
        const float* __restrict__ redw,
        unsigned* __restrict__ bar)
{
    __shared__ float xl[4][14][17][4];
    __shared__ float uu[49*68];           // tl (phase 1) then wl (phase 2)

    const int wid = blockIdx.x;
    const int slot = wid >> 3;
    const int T = (wid & 7)*37 + (slot >> 2);
    const int g = slot & 3;
    const int ty = (T/17)*8, tx = (T%17)*8;
    const int tid = threadIdx.x;
    const int px = tid & 63;
    const int wv = __builtin_amdgcn_readfirstlane(tid >> 6);
    const int sr = px >> 3, sc = px & 7;

    for (int l = 0; l < 6; ++l) {
        const int doNext = (l < 5);
        const float* x      = (l & 1) ? x1buf : x0buf;
        float*       xout   = (l & 1) ? x0buf : x1buf;
        const float* tread  = (l & 1) ? tBbuf : tAbuf;
        float*       twrite = (l & 1) ? tAbuf : tBbuf;
        if (T < 289)
            inv_layer_body(xl, uu, T, g, ty, tx, tid, px, wv, sr, sc,
                           x, tread, twrite,
                           gam + l*16, bet + l*16,
                           spw + l*3136, spb + l*196,
                           redw + (doNext ? (l+1)*1024 : 0),
                           xout, doNext);
        if (l < 5)
            grid_bar(bar, (unsigned)(l + 1), wid);
    }
}

// --- fallback per-layer kernel (R16 behavior) ------------------------------
__global__ __launch_bounds__(256, 5) void e_kernel(
        const float* __restrict__ x,
        const float* __restrict__ tread,
        float* __restrict__ twrite,
        const float* __restrict__ gamma, const float* __restrict__ beta,
        const float* __restrict__ spanw,
        const float* __restrict__ spanb,
        const float* __restrict__ redwn,
        float* __restrict__ xout,
        const int doNext)
{
    __shared__ float xl[4][14][17][4];
    __shared__ float uu[49*68];
    const int wid = blockIdx.x;
    const int slot = wid >> 3;
    const int T = (wid & 7)*37 + (slot >> 2);
    if (T >= 289) return;
    const int g = slot & 3;
    const int ty = (T/17)*8, tx = (T%17)*8;
    const int tid = threadIdx.x;
    const int px = tid & 63;
    const int wv = __builtin_amdgcn_readfirstlane(tid >> 6);
    const int sr = px >> 3, sc = px & 7;
    inv_layer_body(xl, uu, T, g, ty, tx, tid, px, wv, sr, sc,
                   x, tread, twrite, gamma, beta, spanw, spanb, redwn,
                   xout, doNext);
}

// --- conv_out (64->12, 3x3 valid) + PixelShuffle(2) ------------------------
__global__ __launch_bounds__(256) void conv_out_ps_kernel(
        const float* __restrict__ x, const float* __restrict__ W,
        const float* __restrict__ b, float* __restrict__ out)
{
    __shared__ float xh[64*120];   // [c][10 r][12 cl]
    __shared__ float wl[6912];     // 12*64*9
    const int tid = threadIdx.x;
    const int ty = blockIdx.y*8, tx = blockIdx.x*8;

    for (int idx = tid; idx < 6912; idx += 256) wl[idx] = W[idx];
    for (int idx = tid; idx < 1600; idx += 256) {
        int g = idx/400, rem = idx%400;
        int p100 = rem>>2, q = rem&3;
        int r = p100/10, cl = p100%10;
        float4 v = *(const float4*)(x + (size_t)g*GP
                     + ((size_t)(ty + r + 3)*SP + tx + cl + 3)*16 + q*4);
        int c0 = g*16 + q*4;
        xh[(c0+0)*120 + r*12 + cl] = v.x;
        xh[(c0+1)*120 + r*12 + cl] = v.y;
        xh[(c0+2)*120 + r*12 + cl] = v.z;
        xh[(c0+3)*120 + r*12 + cl] = v.w;
    }
    __syncthreads();

    const int wave = __builtin_amdgcn_readfirstlane(tid >> 6);
    const int lane = tid & 63;
    const int s = lane >> 2, cq = lane & 3;
    const int sr = s >> 1, pc0 = (s & 1)*4;
    float acc[3][4] = {};

    for (int c = cq*16; c < cq*16 + 16; ++c) {
        #pragma unroll
        for (int ky = 0; ky < 3; ++ky) {
            const float* xb = &xh[c*120 + (sr + ky)*12 + pc0];
            float4 xa = *(const float4*)xb;
            float2 xm = *(const float2*)(xb + 4);
            float xr[6] = {xa.x, xa.y, xa.z, xa.w, xm.x, xm.y};
            #pragma unroll
            for (int oj = 0; oj < 3; ++oj) {
                const float* wp = &wl[((wave*3 + oj)*64 + c)*9 + ky*3];
                #pragma unroll
                for (int kx = 0; kx < 3; ++kx) {
                    float wv = wp[kx];
                    #pragma unroll
                    for (int q = 0; q < 4; ++q)
                        acc[oj][q] += wv * xr[kx + q];
                }
            }
        }
    }

    #pragma unroll
    for (int oj = 0; oj < 3; ++oj)
        #pragma unroll
        for (int q = 0; q < 4; ++q) {
            float v = acc[oj][q];
            v += __shfl_xor(v, 1, 64);
            v += __shfl_xor(v, 2, 64);
            acc[oj][q] = v;
        }

    if (cq == 0) {
        #pragma unroll
        for (int oj = 0; oj < 3; ++oj) {
            int o = wave*3 + oj;
            float bo = b[o];
            int c3 = o >> 2, r = (o >> 1) & 1, s2 = o & 1;
            int h = ty + sr;
            #pragma unroll
            for (int q = 0; q < 4; ++q) {
                int w = tx + pc0 + q;
                out[c3*65536 + (2*h + r)*256 + 2*w + s2] = acc[oj][q] + bo;
            }
        }
    }
}

// ---------------------------------------------------------------------------
extern "C" void kernel_launch(void* const* d_in, const int* in_sizes, int n_in,
                              void* d_out, int out_size, void* d_ws, size_t ws_size,
                              hipStream_t stream) {
    const float* inf   = (const float*)d_in[0];
    const float* cinw  = (const float*)d_in[1];
    const float* cinb  = (const float*)d_in[2];
    const float* redw  = (const float*)d_in[3];
    const float* gam   = (const float*)d_in[4];
    const float* bet   = (const float*)d_in[5];
    const float* spw   = (const float*)d_in[6];
    const float* spb   = (const float*)d_in[7];
    const float* cow   = (const float*)d_in[8];
    const float* cob   = (const float*)d_in[9];

    float* ws = (float*)d_ws;
    float* x0 = ws;
    float* x1 = ws + XBUF2;
    float* tA = ws + OFF_TA;
    float* tB = ws + OFF_TB;
    unsigned* bar = (unsigned*)(ws + OFF_BAR);

    conv_in_kernel<<<dim3(80, 4), 256, 0, stream>>>(
        inf, cinw, cinb, x0, x1, tA, redw, bar);

    void* args[] = { (void*)&x0, (void*)&x1, (void*)&tA, (void*)&tB,
                     (void*)&gam, (void*)&bet, (void*)&spw, (void*)&spb,
                     (void*)&redw, (void*)&bar };
    hipError_t ce = hipLaunchCooperativeKernel(
        (const void*)inv_all_kernel, dim3(1184), dim3(256), args, 0, stream);

    float* cur = x0; float* nxt = x1;
    if (ce != hipSuccess) {
        for (int l = 0; l < 6; ++l) {
            const int doNext = (l < 5);
            float* tread  = (l & 1) ? tB : tA;
            float* twrite = (l & 1) ? tA : tB;
            e_kernel<<<1184, 256, 0, stream>>>(
                cur, tread, twrite,
                gam + l*16, bet + l*16,
                spw + l*3136, spb + l*196,
                redw + (doNext ? (l+1)*1024 : 0),
                nxt, doNext);
            float* t = cur; cur = nxt; nxt = t;
        }
    } else {
        cur = x0;                    // 6 layers: x0 -> x1 -> ... -> x0
    }

    conv_out_ps_kernel<<<dim3(16, 16), 256, 0, stream>>>(
        cur, cow, cob, (float*)d_out);
}

// Round 6
// 244.262 us; speedup vs baseline: 1.9973x; 1.9973x over previous
//
#include <hip/hip_runtime.h>

// ---------------------------------------------------------------------------
// ZSSR involution net, fp32. Round 21 = R16 structure (6 e_kernel dispatches,
// best 175.3us; fusion abandoned: R17/R18/R20 showed grid-barrier cost ~65us/
// sync regardless of counter topology). e_kernel v14: GLOBAL-DIRECT einsum.
//  - x is L2-resident (19MB) -> drop xl halo staging entirely; einsum reads
//    the 7x8 float4 window straight from global via precomputed clamped
//    row/col offsets (clamp to 135 lands in the zero border = staged clamp).
//  - DS cycles/WG ~3360 -> ~1870 (einsum LDS reads + stage writes gone).
//  - LDS 28.5KB -> 13.3KB (uu only; ol aliases uu) -> launch_bounds(256,6),
//    6 WG/CU = 24 waves/CU (was 5/20).
//  - redundant neighborhood reads (8.5x) move to the idle VMEM/L1 path.
// All other phases (t-dedup, t16, w-gen, doNext reduce), grid 1184, band
// swizzle, conv_in, conv_out identical to R16. Dispatches: 8.
// Layout: x[4 g][136x136 px][16 ch] channel-last, 3-px zero border.
// ---------------------------------------------------------------------------

#define HH 130
#define SP 136               // padded row stride
#define PPL (SP*SP)          // 18496
#define GP (PPL*16)          // floats per group-plane
#define XBUF2 (4*GP)         // floats per feature buffer
#define TP1 (16900*16)       // one group-partial buffer [px][16]
#define OFF_TA (2*XBUF2)             // set A: 4 buffers
#define OFF_TB (OFF_TA + 4*TP1)      // set B: 4 buffers

// --- conv_in (3->64, 3x3, pad=2) + border zeroing + layer-0 t partials -----
__global__ __launch_bounds__(256) void conv_in_kernel(
        const float* __restrict__ inf, const float* __restrict__ W,
        const float* __restrict__ b, float* __restrict__ x0,
        float* __restrict__ x1, float* __restrict__ tpA,
        const float* __restrict__ redw0) {   // [16][64] layer 0
    const int tid = threadIdx.x;
    if (blockIdx.x >= 67) {
        int idx = ((blockIdx.x - 67)*4 + blockIdx.y)*256 + tid;
        if (idx < 3192) {                      // 1596 border px * 2 buffers
            int bsel = idx & 1, e = idx >> 1;
            int r, c;
            if (e < 816) { r = e/136; c = e%136; if (r >= 3) r += 130; }
            else { int j = e-816; r = 3 + j/6; int m = j%6; c = (m<3)? m : m+130; }
            float* base = (bsel ? x1 : x0) + ((size_t)r*SP + c)*16;
            float4 z = make_float4(0.f,0.f,0.f,0.f);
            #pragma unroll
            for (int g2 = 0; g2 < 4; ++g2)
                #pragma unroll
                for (int q = 0; q < 4; ++q)
                    *(float4*)(base + (size_t)g2*GP + q*4) = z;
        }
        return;
    }
    __shared__ float wl[448];          // [16 ch][27 taps] + bias[16]
    const int g = blockIdx.y;
    for (int i = tid; i < 448; i += 256)
        wl[i] = (i < 432) ? W[g*432 + i] : b[g*16 + (i-432)];
    __syncthreads();
    int px = blockIdx.x*256 + tid;
    int pxc = px < 16900 ? px : 16899;
    int h = pxc/130, w = pxc%130;
    float xv[27];
    #pragma unroll
    for (int i = 0; i < 3; ++i)
      #pragma unroll
      for (int ky = 0; ky < 3; ++ky) {
        int y = h - 2 + ky;
        #pragma unroll
        for (int kx = 0; kx < 3; ++kx) {
            int xx = w - 2 + kx;
            float v = 0.f;
            if ((unsigned)y < 128u && (unsigned)xx < 128u)
                v = inf[i*16384 + y*128 + xx];
            xv[i*9 + ky*3 + kx] = v;
        }
      }
    float acc[16];
    #pragma unroll
    for (int c = 0; c < 16; ++c) {
        float a = wl[432 + c];
        #pragma unroll
        for (int t = 0; t < 27; ++t) a += wl[c*27 + t] * xv[t];
        acc[c] = a;
    }
    if (px < 16900) {
        float* dst = x0 + (size_t)g*GP + ((size_t)(h+3)*SP + (w+3))*16;
        #pragma unroll
        for (int q = 0; q < 4; ++q)
            *(float4*)(dst + q*4) =
                make_float4(acc[q*4], acc[q*4+1], acc[q*4+2], acc[q*4+3]);
        // layer-0 t partial for group g (thread owns all 16 ch; s_load redw0)
        float* td = tpA + (size_t)g*TP1 + (size_t)px*16;
        #pragma unroll
        for (int rq = 0; rq < 4; ++rq) {
            float p0=0.f, p1=0.f, p2=0.f, p3=0.f;
            #pragma unroll
            for (int j = 0; j < 16; ++j) {
                float a = acc[j];
                p0 += redw0[(rq*4+0)*64 + g*16 + j]*a;
                p1 += redw0[(rq*4+1)*64 + g*16 + j]*a;
                p2 += redw0[(rq*4+2)*64 + g*16 + j]*a;
                p3 += redw0[(rq*4+3)*64 + g*16 + j]*a;
            }
            *(float4*)(td + rq*4) = make_float4(p0, p1, p2, p3);
        }
    }
}

// --- e_kernel v14 = R16 v12 with GLOBAL-DIRECT einsum (no xl staging) ------
// grid 1184: wid&7 = band, slot = wid>>3; T = band*37+(slot>>2), g = slot&3.
// LDS: uu only (tl[64][20] then wl[49][68] then ol[64][17], all aliased)
//    = 13328B -> 6 WG/CU at launch_bounds(256,6).
#define TL(p, r)  uu[(p)*20 + (r)]
#define WLK(k, p) uu[(k)*68 + (p)]
__global__ __launch_bounds__(256, 6) void e_kernel(
        const float* __restrict__ x,
        const float* __restrict__ tread,  // 4 partial bufs, this layer
        float* __restrict__ twrite,       // 4 partial bufs, next layer
        const float* __restrict__ gamma, const float* __restrict__ beta,
        const float* __restrict__ spanw,  // [4 g][49 k][16 r]
        const float* __restrict__ spanb,  // [4 g][49]
        const float* __restrict__ redwn,  // [16][64] next layer
        float* __restrict__ xout,
        const int doNext)
{
    __shared__ float uu[49*68];           // tl -> wl -> ol (aliased phases)
    const int wid = blockIdx.x;
    const int slot = wid >> 3;
    const int T = (wid & 7)*37 + (slot >> 2);
    if (T >= 289) return;
    const int g = slot & 3;
    const int ty = (T/17)*8, tx = (T%17)*8;
    const int tid = threadIdx.x;
    const int px = tid & 63;
    const int wv = __builtin_amdgcn_readfirstlane(tid >> 6);
    const int sr = px >> 3, sc = px & 7;

    // ---- t dedup: thread (px,wv) sums r-quad wv across the 4 partials ----
    const int hh = min(ty + sr, HH-1), ww = min(tx + sc, HH-1);
    {
        const size_t toff = ((size_t)hh*HH + ww)*16 + wv*4;
        float4 s = make_float4(0.f,0.f,0.f,0.f);
        #pragma unroll
        for (int gg = 0; gg < 4; ++gg) {
            float4 a = *(const float4*)(tread + (size_t)gg*TP1 + toff);
            s.x += a.x; s.y += a.y; s.z += a.z; s.w += a.w;
        }
        *(float4*)&TL(px, wv*4) = s;       // raw sums (BN applied on read)
    }
    __syncthreads();                       // #1: tl complete

    // ---- read t16 (BN+ReLU) ----
    float t16[16];
    #pragma unroll
    for (int q = 0; q < 4; ++q) {
        float4 v = *(const float4*)&TL(px, q*4);
        t16[q*4+0] = fmaxf(gamma[q*4+0]*v.x + beta[q*4+0], 0.f);
        t16[q*4+1] = fmaxf(gamma[q*4+1]*v.y + beta[q*4+1], 0.f);
        t16[q*4+2] = fmaxf(gamma[q*4+2]*v.z + beta[q*4+2], 0.f);
        t16[q*4+3] = fmaxf(gamma[q*4+3]*v.w + beta[q*4+3], 0.f);
    }
    __syncthreads();                       // #2: tl reads done, wl may write

    // ---- w-gen: lane = pixel, wave = k-chunk (13/12/12/12) ----
    {
        const float* sw = spanw + g*784;   // k,r wave-uniform -> s_load
        const float* sb = spanb + g*49;
        const int k0 = wv ? (wv*12 + 1) : 0;
        #pragma unroll
        for (int j = 0; j < 12; ++j) {
            int k = k0 + j;
            float a = sb[k];
            #pragma unroll
            for (int r = 0; r < 16; ++r) a += sw[k*16 + r] * t16[r];
            WLK(k, px) = a;
        }
        if (wv == 0) {
            float a = sb[12];
            #pragma unroll
            for (int r = 0; r < 16; ++r) a += sw[12*16 + r] * t16[r];
            WLK(12, px) = a;
        }
    }
    __syncthreads();                       // #3: wl complete

    // ---- einsum: 1x2 px register blocking, GLOBAL-direct x reads ----
    // thread t<128: pair pr = t&31 -> (sr2 = pr>>2, sc0 = (pr&3)*2),
    // quad cq2 = t>>5. x window read from global (L2-resident); row/col
    // offsets precomputed with clamp-to-135 (zero border = staged clamp).
    float4 o0 = make_float4(0.f,0.f,0.f,0.f);
    float4 o1 = make_float4(0.f,0.f,0.f,0.f);
    int px0 = 0, cq2 = 0;
    if (tid < 128) {
        cq2 = tid >> 5;                    // 0..3 (wave0: 0,1; wave1: 2,3)
        const int pr = tid & 31;
        const int sr2 = pr >> 2, sc0 = (pr & 3)*2;
        px0 = sr2*8 + sc0;
        const float* xg = x + (size_t)g*GP;
        int ro[7], co[8];
        #pragma unroll
        for (int i = 0; i < 7; ++i) {
            int gr = ty + sr2 + i; gr = gr < SP ? gr : SP-1;
            ro[i] = gr * (SP*16);
        }
        #pragma unroll
        for (int j = 0; j < 8; ++j) {
            int gc = tx + sc0 + j; gc = gc < SP ? gc : SP-1;
            co[j] = gc*16 + cq2*4;
        }
        float4 a0 = make_float4(0.f,0.f,0.f,0.f);
        float4 a1 = make_float4(0.f,0.f,0.f,0.f);
        #pragma unroll
        for (int i = 0; i < 7; ++i) {
            float4 row[8];
            #pragma unroll
            for (int j = 0; j < 8; ++j)
                row[j] = *(const float4*)(xg + ro[i] + co[j]);
            #pragma unroll
            for (int j = 0; j < 7; ++j) {
                float2 wp = *(const float2*)&WLK(i*7 + j, px0);
                a0.x += wp.x*row[j].x;   a0.y += wp.x*row[j].y;
                a0.z += wp.x*row[j].z;   a0.w += wp.x*row[j].w;
                a1.x += wp.y*row[j+1].x; a1.y += wp.y*row[j+1].y;
                a1.z += wp.y*row[j+1].z; a1.w += wp.y*row[j+1].w;
            }
        }
        o0 = make_float4(fmaxf(a0.x,0.f), fmaxf(a0.y,0.f),
                         fmaxf(a0.z,0.f), fmaxf(a0.w,0.f));
        o1 = make_float4(fmaxf(a1.x,0.f), fmaxf(a1.y,0.f),
                         fmaxf(a1.z,0.f), fmaxf(a1.w,0.f));
        const int h2 = ty + sr2, w2 = tx + sc0;
        if (h2 < HH) {
            float* ob = xout + (size_t)g*GP
                        + ((size_t)(h2+3)*SP + (w2+3))*16 + cq2*4;
            if (w2 < HH)     *(float4*)ob        = o0;
            if (w2+1 < HH)   *(float4*)(ob + 16) = o1;
        }
    }

    // ---- next-layer t partial: in-WG reduce via ol (aliases uu) -----------
    if (doNext) {
        float* ol = uu;                    // [64][17]; wl/tl dead after einsum
        __syncthreads();                   // #4: einsum WLK reads done
        if (tid < 128) {
            ol[ px0   *17 + cq2*4 + 0] = o0.x;
            ol[ px0   *17 + cq2*4 + 1] = o0.y;
            ol[ px0   *17 + cq2*4 + 2] = o0.z;
            ol[ px0   *17 + cq2*4 + 3] = o0.w;
            ol[(px0+1)*17 + cq2*4 + 0] = o1.x;
            ol[(px0+1)*17 + cq2*4 + 1] = o1.y;
            ol[(px0+1)*17 + cq2*4 + 2] = o1.z;
            ol[(px0+1)*17 + cq2*4 + 3] = o1.w;
        }
        __syncthreads();                   // #5: ol complete
        // thread (px, rq = wv): partial t rows rq*4..+3 over group's 16 ch
        const int rq = wv;
        float p0=0.f, p1=0.f, p2=0.f, p3=0.f;
        #pragma unroll
        for (int j = 0; j < 16; ++j) {
            float xv = ol[px*17 + j];
            const int c = g*16 + j;        // wave-uniform -> s_load redwn
            p0 += redwn[(rq*4+0)*64 + c]*xv;
            p1 += redwn[(rq*4+1)*64 + c]*xv;
            p2 += redwn[(rq*4+2)*64 + c]*xv;
            p3 += redwn[(rq*4+3)*64 + c]*xv;
        }
        const int hR = ty + sr, wR = tx + sc;
        if (hR < HH && wR < HH)
            *(float4*)(twrite + (size_t)g*TP1
                       + ((size_t)hR*HH + wR)*16 + rq*4) =
                make_float4(p0, p1, p2, p3);
    }
}

// --- conv_out (64->12, 3x3 valid) + PixelShuffle(2) ------------------------
__global__ __launch_bounds__(256) void conv_out_ps_kernel(
        const float* __restrict__ x, const float* __restrict__ W,
        const float* __restrict__ b, float* __restrict__ out)
{
    __shared__ float xh[64*120];   // [c][10 r][12 cl]
    __shared__ float wl[6912];     // 12*64*9
    const int tid = threadIdx.x;
    const int ty = blockIdx.y*8, tx = blockIdx.x*8;

    for (int idx = tid; idx < 6912; idx += 256) wl[idx] = W[idx];
    for (int idx = tid; idx < 1600; idx += 256) {
        int g = idx/400, rem = idx%400;
        int p100 = rem>>2, q = rem&3;
        int r = p100/10, cl = p100%10;
        float4 v = *(const float4*)(x + (size_t)g*GP
                     + ((size_t)(ty + r + 3)*SP + tx + cl + 3)*16 + q*4);
        int c0 = g*16 + q*4;
        xh[(c0+0)*120 + r*12 + cl] = v.x;
        xh[(c0+1)*120 + r*12 + cl] = v.y;
        xh[(c0+2)*120 + r*12 + cl] = v.z;
        xh[(c0+3)*120 + r*12 + cl] = v.w;
    }
    __syncthreads();

    const int wave = __builtin_amdgcn_readfirstlane(tid >> 6);
    const int lane = tid & 63;
    const int s = lane >> 2, cq = lane & 3;
    const int sr = s >> 1, pc0 = (s & 1)*4;
    float acc[3][4] = {};

    for (int c = cq*16; c < cq*16 + 16; ++c) {
        #pragma unroll
        for (int ky = 0; ky < 3; ++ky) {
            const float* xb = &xh[c*120 + (sr + ky)*12 + pc0];
            float4 xa = *(const float4*)xb;
            float2 xm = *(const float2*)(xb + 4);
            float xr[6] = {xa.x, xa.y, xa.z, xa.w, xm.x, xm.y};
            #pragma unroll
            for (int oj = 0; oj < 3; ++oj) {
                const float* wp = &wl[((wave*3 + oj)*64 + c)*9 + ky*3];
                #pragma unroll
                for (int kx = 0; kx < 3; ++kx) {
                    float wv = wp[kx];
                    #pragma unroll
                    for (int q = 0; q < 4; ++q)
                        acc[oj][q] += wv * xr[kx + q];
                }
            }
        }
    }

    #pragma unroll
    for (int oj = 0; oj < 3; ++oj)
        #pragma unroll
        for (int q = 0; q < 4; ++q) {
            float v = acc[oj][q];
            v += __shfl_xor(v, 1, 64);
            v += __shfl_xor(v, 2, 64);
            acc[oj][q] = v;
        }

    if (cq == 0) {
        #pragma unroll
        for (int oj = 0; oj < 3; ++oj) {
            int o = wave*3 + oj;
            float bo = b[o];
            int c3 = o >> 2, r = (o >> 1) & 1, s2 = o & 1;
            int h = ty + sr;
            #pragma unroll
            for (int q = 0; q < 4; ++q) {
                int w = tx + pc0 + q;
                out[c3*65536 + (2*h + r)*256 + 2*w + s2] = acc[oj][q] + bo;
            }
        }
    }
}

// ---------------------------------------------------------------------------
extern "C" void kernel_launch(void* const* d_in, const int* in_sizes, int n_in,
                              void* d_out, int out_size, void* d_ws, size_t ws_size,
                              hipStream_t stream) {
    const float* inf   = (const float*)d_in[0];
    const float* cinw  = (const float*)d_in[1];
    const float* cinb  = (const float*)d_in[2];
    const float* redw  = (const float*)d_in[3];
    const float* gam   = (const float*)d_in[4];
    const float* bet   = (const float*)d_in[5];
    const float* spw   = (const float*)d_in[6];
    const float* spb   = (const float*)d_in[7];
    const float* cow   = (const float*)d_in[8];
    const float* cob   = (const float*)d_in[9];

    float* ws = (float*)d_ws;
    float* x0 = ws;
    float* x1 = ws + XBUF2;
    float* tA = ws + OFF_TA;
    float* tB = ws + OFF_TB;

    conv_in_kernel<<<dim3(80, 4), 256, 0, stream>>>(
        inf, cinw, cinb, x0, x1, tA, redw);

    float* cur = x0; float* nxt = x1;
    for (int l = 0; l < 6; ++l) {
        const int doNext = (l < 5);
        float* tread  = (l & 1) ? tB : tA;
        float* twrite = (l & 1) ? tA : tB;
        e_kernel<<<1184, 256, 0, stream>>>(
            cur, tread, twrite,
            gam + l*16, bet + l*16,
            spw + l*3136, spb + l*196,
            redw + (doNext ? (l+1)*1024 : 0),
            nxt, doNext);
        float* t = cur; cur = nxt; nxt = t;
    }

    conv_out_ps_kernel<<<dim3(16, 16), 256, 0, stream>>>(
        cur, cow, cob, (float*)d_out);
}

// Round 7
// 175.329 us; speedup vs baseline: 2.7825x; 1.3932x over previous
//
#include <hip/hip_runtime.h>

// ---------------------------------------------------------------------------
// ZSSR involution net, fp32. Round 22 = R16 (175.3us, best) with LDS shaved
// to fit 6 WG/CU (was 5): xl[4][14][17][4] -> [4][14][15][4] (13440B, 15>=14
// cols needed), uu stride 68 -> 66 (12936B). Total 26376B <= 160K/6=26624.
// launch_bounds(256,6): 24 waves/CU for better VMEM-latency hiding in the
// t-dedup/stage phases. Bank patterns re-verified: einsum xl start-bank
// uniform (28 = -4 mod 32 bijection over sr2); wl b64 2-way (free); others
// unchanged. Everything else byte-identical to R16. Dispatches: 8.
// History: R17/R18/R20 fusion abandoned (device-scope barrier ~65us = XCD L2
// coherence, not RMW serialization); R19 16x8@3WG regressed; R21 global-
// direct einsum regressed (VMEM latency >> LDS). Body is DS/latency-bound.
// Layout: x[4 g][136x136 px][16 ch] channel-last, 3-px zero border.
// ---------------------------------------------------------------------------

#define HH 130
#define SP 136               // padded row stride
#define PPL (SP*SP)          // 18496
#define GP (PPL*16)          // floats per group-plane
#define XBUF2 (4*GP)         // floats per feature buffer
#define TP1 (16900*16)       // one group-partial buffer [px][16]
#define OFF_TA (2*XBUF2)             // set A: 4 buffers
#define OFF_TB (OFF_TA + 4*TP1)      // set B: 4 buffers

// --- conv_in (3->64, 3x3, pad=2) + border zeroing + layer-0 t partials -----
__global__ __launch_bounds__(256) void conv_in_kernel(
        const float* __restrict__ inf, const float* __restrict__ W,
        const float* __restrict__ b, float* __restrict__ x0,
        float* __restrict__ x1, float* __restrict__ tpA,
        const float* __restrict__ redw0) {   // [16][64] layer 0
    const int tid = threadIdx.x;
    if (blockIdx.x >= 67) {
        int idx = ((blockIdx.x - 67)*4 + blockIdx.y)*256 + tid;
        if (idx < 3192) {                      // 1596 border px * 2 buffers
            int bsel = idx & 1, e = idx >> 1;
            int r, c;
            if (e < 816) { r = e/136; c = e%136; if (r >= 3) r += 130; }
            else { int j = e-816; r = 3 + j/6; int m = j%6; c = (m<3)? m : m+130; }
            float* base = (bsel ? x1 : x0) + ((size_t)r*SP + c)*16;
            float4 z = make_float4(0.f,0.f,0.f,0.f);
            #pragma unroll
            for (int g2 = 0; g2 < 4; ++g2)
                #pragma unroll
                for (int q = 0; q < 4; ++q)
                    *(float4*)(base + (size_t)g2*GP + q*4) = z;
        }
        return;
    }
    __shared__ float wl[448];          // [16 ch][27 taps] + bias[16]
    const int g = blockIdx.y;
    for (int i = tid; i < 448; i += 256)
        wl[i] = (i < 432) ? W[g*432 + i] : b[g*16 + (i-432)];
    __syncthreads();
    int px = blockIdx.x*256 + tid;
    int pxc = px < 16900 ? px : 16899;
    int h = pxc/130, w = pxc%130;
    float xv[27];
    #pragma unroll
    for (int i = 0; i < 3; ++i)
      #pragma unroll
      for (int ky = 0; ky < 3; ++ky) {
        int y = h - 2 + ky;
        #pragma unroll
        for (int kx = 0; kx < 3; ++kx) {
            int xx = w - 2 + kx;
            float v = 0.f;
            if ((unsigned)y < 128u && (unsigned)xx < 128u)
                v = inf[i*16384 + y*128 + xx];
            xv[i*9 + ky*3 + kx] = v;
        }
      }
    float acc[16];
    #pragma unroll
    for (int c = 0; c < 16; ++c) {
        float a = wl[432 + c];
        #pragma unroll
        for (int t = 0; t < 27; ++t) a += wl[c*27 + t] * xv[t];
        acc[c] = a;
    }
    if (px < 16900) {
        float* dst = x0 + (size_t)g*GP + ((size_t)(h+3)*SP + (w+3))*16;
        #pragma unroll
        for (int q = 0; q < 4; ++q)
            *(float4*)(dst + q*4) =
                make_float4(acc[q*4], acc[q*4+1], acc[q*4+2], acc[q*4+3]);
        // layer-0 t partial for group g (thread owns all 16 ch; s_load redw0)
        float* td = tpA + (size_t)g*TP1 + (size_t)px*16;
        #pragma unroll
        for (int rq = 0; rq < 4; ++rq) {
            float p0=0.f, p1=0.f, p2=0.f, p3=0.f;
            #pragma unroll
            for (int j = 0; j < 16; ++j) {
                float a = acc[j];
                p0 += redw0[(rq*4+0)*64 + g*16 + j]*a;
                p1 += redw0[(rq*4+1)*64 + g*16 + j]*a;
                p2 += redw0[(rq*4+2)*64 + g*16 + j]*a;
                p3 += redw0[(rq*4+3)*64 + g*16 + j]*a;
            }
            *(float4*)(td + rq*4) = make_float4(p0, p1, p2, p3);
        }
    }
}

// --- e_kernel v15 = R16 v12 with LDS shave -> 6 WG/CU ----------------------
// grid 1184: wid&7 = band, slot = wid>>3; T = band*37+(slot>>2), g = slot&3.
// LDS: xl[4][14][15][4] 13440B + uu (tl[64][20] ALIAS wl[49][66]) 12936B
//    = 26376B -> 6 WG/CU at launch_bounds(256,6).
#define TL(p, r)  uu[(p)*20 + (r)]
#define WLK(k, p) uu[(k)*66 + (p)]
__global__ __launch_bounds__(256, 6) void e_kernel(
        const float* __restrict__ x,
        const float* __restrict__ tread,  // 4 partial bufs, this layer
        float* __restrict__ twrite,       // 4 partial bufs, next layer
        const float* __restrict__ gamma, const float* __restrict__ beta,
        const float* __restrict__ spanw,  // [4 g][49 k][16 r]
        const float* __restrict__ spanb,  // [4 g][49]
        const float* __restrict__ redwn,  // [16][64] next layer
        float* __restrict__ xout,
        const int doNext)
{
    __shared__ float xl[4][14][15][4];
    __shared__ float uu[49*66];           // tl (phase 1) then wl (phase 2)
    const int wid = blockIdx.x;
    const int slot = wid >> 3;
    const int T = (wid & 7)*37 + (slot >> 2);
    if (T >= 289) return;
    const int g = slot & 3;
    const int ty = (T/17)*8, tx = (T%17)*8;
    const int tid = threadIdx.x;
    const int px = tid & 63;
    const int wv = __builtin_amdgcn_readfirstlane(tid >> 6);
    const int sr = px >> 3, sc = px & 7;

    // ---- stage halo: 14x14 px, 4 quads (group g's 16 ch) ----
    for (int i = tid; i < 784; i += 256) {
        int q = i & 3, p = i >> 2;
        int r = p / 14, c = p % 14;
        int gr = ty + r, gc = tx + c;
        gr = gr < SP ? gr : SP-1;          // clamp lands in zero border
        gc = gc < SP ? gc : SP-1;
        float4 v = *(const float4*)(x + (size_t)g*GP
                                    + ((size_t)gr*SP + gc)*16 + q*4);
        *(float4*)&xl[q][r][c][0] = v;
    }

    // ---- t dedup: thread (px,wv) sums r-quad wv across the 4 partials ----
    const int hh = min(ty + sr, HH-1), ww = min(tx + sc, HH-1);
    {
        const size_t toff = ((size_t)hh*HH + ww)*16 + wv*4;
        float4 s = make_float4(0.f,0.f,0.f,0.f);
        #pragma unroll
        for (int gg = 0; gg < 4; ++gg) {
            float4 a = *(const float4*)(tread + (size_t)gg*TP1 + toff);
            s.x += a.x; s.y += a.y; s.z += a.z; s.w += a.w;
        }
        *(float4*)&TL(px, wv*4) = s;       // raw sums (BN applied on read)
    }
    __syncthreads();                       // #1: tl complete

    // ---- read t16 (BN+ReLU) ----
    float t16[16];
    #pragma unroll
    for (int q = 0; q < 4; ++q) {
        float4 v = *(const float4*)&TL(px, q*4);
        t16[q*4+0] = fmaxf(gamma[q*4+0]*v.x + beta[q*4+0], 0.f);
        t16[q*4+1] = fmaxf(gamma[q*4+1]*v.y + beta[q*4+1], 0.f);
        t16[q*4+2] = fmaxf(gamma[q*4+2]*v.z + beta[q*4+2], 0.f);
        t16[q*4+3] = fmaxf(gamma[q*4+3]*v.w + beta[q*4+3], 0.f);
    }
    __syncthreads();                       // #2: tl reads done, wl may write

    // ---- w-gen: lane = pixel, wave = k-chunk (13/12/12/12) ----
    {
        const float* sw = spanw + g*784;   // k,r wave-uniform -> s_load
        const float* sb = spanb + g*49;
        const int k0 = wv ? (wv*12 + 1) : 0;
        #pragma unroll
        for (int j = 0; j < 12; ++j) {
            int k = k0 + j;
            float a = sb[k];
            #pragma unroll
            for (int r = 0; r < 16; ++r) a += sw[k*16 + r] * t16[r];
            WLK(k, px) = a;
        }
        if (wv == 0) {
            float a = sb[12];
            #pragma unroll
            for (int r = 0; r < 16; ++r) a += sw[12*16 + r] * t16[r];
            WLK(12, px) = a;
        }
    }
    __syncthreads();                       // #3: wl complete (and halo in xl)

    // ---- einsum: 1x2 px register blocking, waves 0-1 only ----
    float4 o0 = make_float4(0.f,0.f,0.f,0.f);
    float4 o1 = make_float4(0.f,0.f,0.f,0.f);
    int px0 = 0, cq2 = 0;
    if (tid < 128) {
        cq2 = tid >> 5;                    // 0..3 (wave0: 0,1; wave1: 2,3)
        const int pr = tid & 31;
        const int sr2 = pr >> 2, sc0 = (pr & 3)*2;
        px0 = sr2*8 + sc0;
        float4 a0 = make_float4(0.f,0.f,0.f,0.f);
        float4 a1 = make_float4(0.f,0.f,0.f,0.f);
        #pragma unroll
        for (int i = 0; i < 7; ++i) {
            float4 row[8];
            #pragma unroll
            for (int j = 0; j < 8; ++j)
                row[j] = *(const float4*)&xl[cq2][sr2 + i][sc0 + j][0];
            #pragma unroll
            for (int j = 0; j < 7; ++j) {
                float2 wp = *(const float2*)&WLK(i*7 + j, px0);
                a0.x += wp.x*row[j].x;   a0.y += wp.x*row[j].y;
                a0.z += wp.x*row[j].z;   a0.w += wp.x*row[j].w;
                a1.x += wp.y*row[j+1].x; a1.y += wp.y*row[j+1].y;
                a1.z += wp.y*row[j+1].z; a1.w += wp.y*row[j+1].w;
            }
        }
        o0 = make_float4(fmaxf(a0.x,0.f), fmaxf(a0.y,0.f),
                         fmaxf(a0.z,0.f), fmaxf(a0.w,0.f));
        o1 = make_float4(fmaxf(a1.x,0.f), fmaxf(a1.y,0.f),
                         fmaxf(a1.z,0.f), fmaxf(a1.w,0.f));
        const int h2 = ty + sr2, w2 = tx + sc0;
        if (h2 < HH) {
            float* ob = xout + (size_t)g*GP
                        + ((size_t)(h2+3)*SP + (w2+3))*16 + cq2*4;
            if (w2 < HH)     *(float4*)ob        = o0;
            if (w2+1 < HH)   *(float4*)(ob + 16) = o1;
        }
    }

    // ---- next-layer t partial: in-WG reduce via dead xl, plain stores -----
    if (doNext) {
        float* ol = (float*)xl;            // [64][17], 2-way banks
        __syncthreads();                   // einsum reads of xl done
        if (tid < 128) {
            ol[ px0   *17 + cq2*4 + 0] = o0.x;
            ol[ px0   *17 + cq2*4 + 1] = o0.y;
            ol[ px0   *17 + cq2*4 + 2] = o0.z;
            ol[ px0   *17 + cq2*4 + 3] = o0.w;
            ol[(px0+1)*17 + cq2*4 + 0] = o1.x;
            ol[(px0+1)*17 + cq2*4 + 1] = o1.y;
            ol[(px0+1)*17 + cq2*4 + 2] = o1.z;
            ol[(px0+1)*17 + cq2*4 + 3] = o1.w;
        }
        __syncthreads();
        // thread (px, rq = wv): partial t rows rq*4..+3 over group's 16 ch
        const int rq = wv;
        float p0=0.f, p1=0.f, p2=0.f, p3=0.f;
        #pragma unroll
        for (int j = 0; j < 16; ++j) {
            float xv = ol[px*17 + j];
            const int c = g*16 + j;        // wave-uniform -> s_load redwn
            p0 += redwn[(rq*4+0)*64 + c]*xv;
            p1 += redwn[(rq*4+1)*64 + c]*xv;
            p2 += redwn[(rq*4+2)*64 + c]*xv;
            p3 += redwn[(rq*4+3)*64 + c]*xv;
        }
        const int hR = ty + sr, wR = tx + sc;
        if (hR < HH && wR < HH)
            *(float4*)(twrite + (size_t)g*TP1
                       + ((size_t)hR*HH + wR)*16 + rq*4) =
                make_float4(p0, p1, p2, p3);
    }
}

// --- conv_out (64->12, 3x3 valid) + PixelShuffle(2) ------------------------
__global__ __launch_bounds__(256) void conv_out_ps_kernel(
        const float* __restrict__ x, const float* __restrict__ W,
        const float* __restrict__ b, float* __restrict__ out)
{
    __shared__ float xh[64*120];   // [c][10 r][12 cl]
    __shared__ float wl[6912];     // 12*64*9
    const int tid = threadIdx.x;
    const int ty = blockIdx.y*8, tx = blockIdx.x*8;

    for (int idx = tid; idx < 6912; idx += 256) wl[idx] = W[idx];
    for (int idx = tid; idx < 1600; idx += 256) {
        int g = idx/400, rem = idx%400;
        int p100 = rem>>2, q = rem&3;
        int r = p100/10, cl = p100%10;
        float4 v = *(const float4*)(x + (size_t)g*GP
                     + ((size_t)(ty + r + 3)*SP + tx + cl + 3)*16 + q*4);
        int c0 = g*16 + q*4;
        xh[(c0+0)*120 + r*12 + cl] = v.x;
        xh[(c0+1)*120 + r*12 + cl] = v.y;
        xh[(c0+2)*120 + r*12 + cl] = v.z;
        xh[(c0+3)*120 + r*12 + cl] = v.w;
    }
    __syncthreads();

    const int wave = __builtin_amdgcn_readfirstlane(tid >> 6);
    const int lane = tid & 63;
    const int s = lane >> 2, cq = lane & 3;
    const int sr = s >> 1, pc0 = (s & 1)*4;
    float acc[3][4] = {};

    for (int c = cq*16; c < cq*16 + 16; ++c) {
        #pragma unroll
        for (int ky = 0; ky < 3; ++ky) {
            const float* xb = &xh[c*120 + (sr + ky)*12 + pc0];
            float4 xa = *(const float4*)xb;
            float2 xm = *(const float2*)(xb + 4);
            float xr[6] = {xa.x, xa.y, xa.z, xa.w, xm.x, xm.y};
            #pragma unroll
            for (int oj = 0; oj < 3; ++oj) {
                const float* wp = &wl[((wave*3 + oj)*64 + c)*9 + ky*3];
                #pragma unroll
                for (int kx = 0; kx < 3; ++kx) {
                    float wv = wp[kx];
                    #pragma unroll
                    for (int q = 0; q < 4; ++q)
                        acc[oj][q] += wv * xr[kx + q];
                }
            }
        }
    }

    #pragma unroll
    for (int oj = 0; oj < 3; ++oj)
        #pragma unroll
        for (int q = 0; q < 4; ++q) {
            float v = acc[oj][q];
            v += __shfl_xor(v, 1, 64);
            v += __shfl_xor(v, 2, 64);
            acc[oj][q] = v;
        }

    if (cq == 0) {
        #pragma unroll
        for (int oj = 0; oj < 3; ++oj) {
            int o = wave*3 + oj;
            float bo = b[o];
            int c3 = o >> 2, r = (o >> 1) & 1, s2 = o & 1;
            int h = ty + sr;
            #pragma unroll
            for (int q = 0; q < 4; ++q) {
                int w = tx + pc0 + q;
                out[c3*65536 + (2*h + r)*256 + 2*w + s2] = acc[oj][q] + bo;
            }
        }
    }
}

// ---------------------------------------------------------------------------
extern "C" void kernel_launch(void* const* d_in, const int* in_sizes, int n_in,
                              void* d_out, int out_size, void* d_ws, size_t ws_size,
                              hipStream_t stream) {
    const float* inf   = (const float*)d_in[0];
    const float* cinw  = (const float*)d_in[1];
    const float* cinb  = (const float*)d_in[2];
    const float* redw  = (const float*)d_in[3];
    const float* gam   = (const float*)d_in[4];
    const float* bet   = (const float*)d_in[5];
    const float* spw   = (const float*)d_in[6];
    const float* spb   = (const float*)d_in[7];
    const float* cow   = (const float*)d_in[8];
    const float* cob   = (const float*)d_in[9];

    float* ws = (float*)d_ws;
    float* x0 = ws;
    float* x1 = ws + XBUF2;
    float* tA = ws + OFF_TA;
    float* tB = ws + OFF_TB;

    conv_in_kernel<<<dim3(80, 4), 256, 0, stream>>>(
        inf, cinw, cinb, x0, x1, tA, redw);

    float* cur = x0; float* nxt = x1;
    for (int l = 0; l < 6; ++l) {
        const int doNext = (l < 5);
        float* tread  = (l & 1) ? tB : tA;
        float* twrite = (l & 1) ? tA : tB;
        e_kernel<<<1184, 256, 0, stream>>>(
            cur, tread, twrite,
            gam + l*16, bet + l*16,
            spw + l*3136, spb + l*196,
            redw + (doNext ? (l+1)*1024 : 0),
            nxt, doNext);
        float* t = cur; cur = nxt; nxt = t;
    }

    conv_out_ps_kernel<<<dim3(16, 16), 256, 0, stream>>>(
        cur, cow, cob, (float*)d_out);
}

// Round 8
// 173.892 us; speedup vs baseline: 2.8055x; 1.0083x over previous
//
#include <hip/hip_runtime.h>

// ---------------------------------------------------------------------------
// ZSSR involution net, fp32. Round 23 = R16/R22 structure with e_kernel v16:
// einsum register blocking widened 1x2 -> 1x4 (one wave: 16 px-groups x 4
// ch-quads; 4 adjacent px per thread). Per window row: 10-wide float4 strip
// loaded once (70 b128, was 112-equiv) and per-k weights for 4 px read as ONE
// b128 (49, was 98 b64). Einsum DS wave-instr 210 -> 119 (-43%); body DS
// ~3180 -> ~2560 cyc/WG. uu stride 66 -> 68 (16B alignment for WLK b128);
// xl[4][14][15][4] kept. LDS 26768B -> 5 WG/CU (R22 proved 5 vs 6 is a wash).
// History: fusion dead (65us/barrier = XCD L2 coherence, R17/R18/R20);
// 16x8@3WG dead (R19); global-direct einsum dead (R21); occupancy dead (R22).
// Body is DS-throughput-bound; this cuts DS instructions directly.
// Layout: x[4 g][136x136 px][16 ch] channel-last, 3-px zero border.
// ---------------------------------------------------------------------------

#define HH 130
#define SP 136               // padded row stride
#define PPL (SP*SP)          // 18496
#define GP (PPL*16)          // floats per group-plane
#define XBUF2 (4*GP)         // floats per feature buffer
#define TP1 (16900*16)       // one group-partial buffer [px][16]
#define OFF_TA (2*XBUF2)             // set A: 4 buffers
#define OFF_TB (OFF_TA + 4*TP1)      // set B: 4 buffers

// --- conv_in (3->64, 3x3, pad=2) + border zeroing + layer-0 t partials -----
__global__ __launch_bounds__(256) void conv_in_kernel(
        const float* __restrict__ inf, const float* __restrict__ W,
        const float* __restrict__ b, float* __restrict__ x0,
        float* __restrict__ x1, float* __restrict__ tpA,
        const float* __restrict__ redw0) {   // [16][64] layer 0
    const int tid = threadIdx.x;
    if (blockIdx.x >= 67) {
        int idx = ((blockIdx.x - 67)*4 + blockIdx.y)*256 + tid;
        if (idx < 3192) {                      // 1596 border px * 2 buffers
            int bsel = idx & 1, e = idx >> 1;
            int r, c;
            if (e < 816) { r = e/136; c = e%136; if (r >= 3) r += 130; }
            else { int j = e-816; r = 3 + j/6; int m = j%6; c = (m<3)? m : m+130; }
            float* base = (bsel ? x1 : x0) + ((size_t)r*SP + c)*16;
            float4 z = make_float4(0.f,0.f,0.f,0.f);
            #pragma unroll
            for (int g2 = 0; g2 < 4; ++g2)
                #pragma unroll
                for (int q = 0; q < 4; ++q)
                    *(float4*)(base + (size_t)g2*GP + q*4) = z;
        }
        return;
    }
    __shared__ float wl[448];          // [16 ch][27 taps] + bias[16]
    const int g = blockIdx.y;
    for (int i = tid; i < 448; i += 256)
        wl[i] = (i < 432) ? W[g*432 + i] : b[g*16 + (i-432)];
    __syncthreads();
    int px = blockIdx.x*256 + tid;
    int pxc = px < 16900 ? px : 16899;
    int h = pxc/130, w = pxc%130;
    float xv[27];
    #pragma unroll
    for (int i = 0; i < 3; ++i)
      #pragma unroll
      for (int ky = 0; ky < 3; ++ky) {
        int y = h - 2 + ky;
        #pragma unroll
        for (int kx = 0; kx < 3; ++kx) {
            int xx = w - 2 + kx;
            float v = 0.f;
            if ((unsigned)y < 128u && (unsigned)xx < 128u)
                v = inf[i*16384 + y*128 + xx];
            xv[i*9 + ky*3 + kx] = v;
        }
      }
    float acc[16];
    #pragma unroll
    for (int c = 0; c < 16; ++c) {
        float a = wl[432 + c];
        #pragma unroll
        for (int t = 0; t < 27; ++t) a += wl[c*27 + t] * xv[t];
        acc[c] = a;
    }
    if (px < 16900) {
        float* dst = x0 + (size_t)g*GP + ((size_t)(h+3)*SP + (w+3))*16;
        #pragma unroll
        for (int q = 0; q < 4; ++q)
            *(float4*)(dst + q*4) =
                make_float4(acc[q*4], acc[q*4+1], acc[q*4+2], acc[q*4+3]);
        // layer-0 t partial for group g (thread owns all 16 ch; s_load redw0)
        float* td = tpA + (size_t)g*TP1 + (size_t)px*16;
        #pragma unroll
        for (int rq = 0; rq < 4; ++rq) {
            float p0=0.f, p1=0.f, p2=0.f, p3=0.f;
            #pragma unroll
            for (int j = 0; j < 16; ++j) {
                float a = acc[j];
                p0 += redw0[(rq*4+0)*64 + g*16 + j]*a;
                p1 += redw0[(rq*4+1)*64 + g*16 + j]*a;
                p2 += redw0[(rq*4+2)*64 + g*16 + j]*a;
                p3 += redw0[(rq*4+3)*64 + g*16 + j]*a;
            }
            *(float4*)(td + rq*4) = make_float4(p0, p1, p2, p3);
        }
    }
}

// --- e_kernel v16 = v12 with 1x4-px einsum (one wave) ----------------------
// grid 1184: wid&7 = band, slot = wid>>3; T = band*37+(slot>>2), g = slot&3.
// LDS: xl[4][14][15][4] 13440B + uu (tl[64][20] ALIAS wl[49][68]) 13328B
//    = 26768B -> 5 WG/CU at launch_bounds(256,5).
#define TL(p, r)  uu[(p)*20 + (r)]
#define WLK(k, p) uu[(k)*68 + (p)]
__global__ __launch_bounds__(256, 5) void e_kernel(
        const float* __restrict__ x,
        const float* __restrict__ tread,  // 4 partial bufs, this layer
        float* __restrict__ twrite,       // 4 partial bufs, next layer
        const float* __restrict__ gamma, const float* __restrict__ beta,
        const float* __restrict__ spanw,  // [4 g][49 k][16 r]
        const float* __restrict__ spanb,  // [4 g][49]
        const float* __restrict__ redwn,  // [16][64] next layer
        float* __restrict__ xout,
        const int doNext)
{
    __shared__ float xl[4][14][15][4];
    __shared__ float uu[49*68];           // tl (phase 1) then wl (phase 2)
    const int wid = blockIdx.x;
    const int slot = wid >> 3;
    const int T = (wid & 7)*37 + (slot >> 2);
    if (T >= 289) return;
    const int g = slot & 3;
    const int ty = (T/17)*8, tx = (T%17)*8;
    const int tid = threadIdx.x;
    const int px = tid & 63;
    const int wv = __builtin_amdgcn_readfirstlane(tid >> 6);
    const int sr = px >> 3, sc = px & 7;

    // ---- stage halo: 14x14 px, 4 quads (group g's 16 ch) ----
    for (int i = tid; i < 784; i += 256) {
        int q = i & 3, p = i >> 2;
        int r = p / 14, c = p % 14;
        int gr = ty + r, gc = tx + c;
        gr = gr < SP ? gr : SP-1;          // clamp lands in zero border
        gc = gc < SP ? gc : SP-1;
        float4 v = *(const float4*)(x + (size_t)g*GP
                                    + ((size_t)gr*SP + gc)*16 + q*4);
        *(float4*)&xl[q][r][c][0] = v;
    }

    // ---- t dedup: thread (px,wv) sums r-quad wv across the 4 partials ----
    const int hh = min(ty + sr, HH-1), ww = min(tx + sc, HH-1);
    {
        const size_t toff = ((size_t)hh*HH + ww)*16 + wv*4;
        float4 s = make_float4(0.f,0.f,0.f,0.f);
        #pragma unroll
        for (int gg = 0; gg < 4; ++gg) {
            float4 a = *(const float4*)(tread + (size_t)gg*TP1 + toff);
            s.x += a.x; s.y += a.y; s.z += a.z; s.w += a.w;
        }
        *(float4*)&TL(px, wv*4) = s;       // raw sums (BN applied on read)
    }
    __syncthreads();                       // #1: tl complete

    // ---- read t16 (BN+ReLU) ----
    float t16[16];
    #pragma unroll
    for (int q = 0; q < 4; ++q) {
        float4 v = *(const float4*)&TL(px, q*4);
        t16[q*4+0] = fmaxf(gamma[q*4+0]*v.x + beta[q*4+0], 0.f);
        t16[q*4+1] = fmaxf(gamma[q*4+1]*v.y + beta[q*4+1], 0.f);
        t16[q*4+2] = fmaxf(gamma[q*4+2]*v.z + beta[q*4+2], 0.f);
        t16[q*4+3] = fmaxf(gamma[q*4+3]*v.w + beta[q*4+3], 0.f);
    }
    __syncthreads();                       // #2: tl reads done, wl may write

    // ---- w-gen: lane = pixel, wave = k-chunk (13/12/12/12) ----
    {
        const float* sw = spanw + g*784;   // k,r wave-uniform -> s_load
        const float* sb = spanb + g*49;
        const int k0 = wv ? (wv*12 + 1) : 0;
        #pragma unroll
        for (int j = 0; j < 12; ++j) {
            int k = k0 + j;
            float a = sb[k];
            #pragma unroll
            for (int r = 0; r < 16; ++r) a += sw[k*16 + r] * t16[r];
            WLK(k, px) = a;
        }
        if (wv == 0) {
            float a = sb[12];
            #pragma unroll
            for (int r = 0; r < 16; ++r) a += sw[12*16 + r] * t16[r];
            WLK(12, px) = a;
        }
    }
    __syncthreads();                       // #3: wl complete (and halo in xl)

    // ---- einsum: 1x4 px register blocking, ONE wave (tid<64) ----
    // cq2 = tid>>4 (quad), pr = tid&15: sr2 = pr>>1, sc0 = (pr&1)*4.
    // Per window row: 10-wide float4 strip read once, slid across 4 px;
    // weights for px0..px0+3 come as one b128 (16B-aligned: stride 68).
    float4 o0 = make_float4(0.f,0.f,0.f,0.f);
    float4 o1 = o0, o2 = o0, o3 = o0;
    int px0 = 0, cq2 = 0;
    if (tid < 64) {
        cq2 = tid >> 4;
        const int pr = tid & 15;
        const int sr2 = pr >> 1, sc0 = (pr & 1)*4;
        px0 = sr2*8 + sc0;
        float4 a0 = make_float4(0.f,0.f,0.f,0.f);
        float4 a1 = a0, a2 = a0, a3 = a0;
        #pragma unroll
        for (int i = 0; i < 7; ++i) {
            float4 row[10];
            #pragma unroll
            for (int j = 0; j < 10; ++j)
                row[j] = *(const float4*)&xl[cq2][sr2 + i][sc0 + j][0];
            #pragma unroll
            for (int j = 0; j < 7; ++j) {
                float4 wp = *(const float4*)&WLK(i*7 + j, px0);
                a0.x += wp.x*row[j  ].x; a0.y += wp.x*row[j  ].y;
                a0.z += wp.x*row[j  ].z; a0.w += wp.x*row[j  ].w;
                a1.x += wp.y*row[j+1].x; a1.y += wp.y*row[j+1].y;
                a1.z += wp.y*row[j+1].z; a1.w += wp.y*row[j+1].w;
                a2.x += wp.z*row[j+2].x; a2.y += wp.z*row[j+2].y;
                a2.z += wp.z*row[j+2].z; a2.w += wp.z*row[j+2].w;
                a3.x += wp.w*row[j+3].x; a3.y += wp.w*row[j+3].y;
                a3.z += wp.w*row[j+3].z; a3.w += wp.w*row[j+3].w;
            }
        }
        o0 = make_float4(fmaxf(a0.x,0.f), fmaxf(a0.y,0.f),
                         fmaxf(a0.z,0.f), fmaxf(a0.w,0.f));
        o1 = make_float4(fmaxf(a1.x,0.f), fmaxf(a1.y,0.f),
                         fmaxf(a1.z,0.f), fmaxf(a1.w,0.f));
        o2 = make_float4(fmaxf(a2.x,0.f), fmaxf(a2.y,0.f),
                         fmaxf(a2.z,0.f), fmaxf(a2.w,0.f));
        o3 = make_float4(fmaxf(a3.x,0.f), fmaxf(a3.y,0.f),
                         fmaxf(a3.z,0.f), fmaxf(a3.w,0.f));
        const int h2 = ty + sr2, w2 = tx + sc0;
        if (h2 < HH) {
            float* ob = xout + (size_t)g*GP
                        + ((size_t)(h2+3)*SP + (w2+3))*16 + cq2*4;
            if (w2   < HH) *(float4*)(ob)      = o0;
            if (w2+1 < HH) *(float4*)(ob + 16) = o1;
            if (w2+2 < HH) *(float4*)(ob + 32) = o2;
            if (w2+3 < HH) *(float4*)(ob + 48) = o3;
        }
    }

    // ---- next-layer t partial: in-WG reduce via dead xl, plain stores -----
    if (doNext) {
        float* ol = (float*)xl;            // [64][17]
        __syncthreads();                   // einsum reads of xl done
        if (tid < 64) {
            #pragma unroll
            for (int e = 0; e < 4; ++e) {
                ol[(px0+0)*17 + cq2*4 + e] = (&o0.x)[e];
                ol[(px0+1)*17 + cq2*4 + e] = (&o1.x)[e];
                ol[(px0+2)*17 + cq2*4 + e] = (&o2.x)[e];
                ol[(px0+3)*17 + cq2*4 + e] = (&o3.x)[e];
            }
        }
        __syncthreads();
        // thread (px, rq = wv): partial t rows rq*4..+3 over group's 16 ch
        const int rq = wv;
        float p0=0.f, p1=0.f, p2=0.f, p3=0.f;
        #pragma unroll
        for (int j = 0; j < 16; ++j) {
            float xv = ol[px*17 + j];
            const int c = g*16 + j;        // wave-uniform -> s_load redwn
            p0 += redwn[(rq*4+0)*64 + c]*xv;
            p1 += redwn[(rq*4+1)*64 + c]*xv;
            p2 += redwn[(rq*4+2)*64 + c]*xv;
            p3 += redwn[(rq*4+3)*64 + c]*xv;
        }
        const int hR = ty + sr, wR = tx + sc;
        if (hR < HH && wR < HH)
            *(float4*)(twrite + (size_t)g*TP1
                       + ((size_t)hR*HH + wR)*16 + rq*4) =
                make_float4(p0, p1, p2, p3);
    }
}

// --- conv_out (64->12, 3x3 valid) + PixelShuffle(2) ------------------------
__global__ __launch_bounds__(256) void conv_out_ps_kernel(
        const float* __restrict__ x, const float* __restrict__ W,
        const float* __restrict__ b, float* __restrict__ out)
{
    __shared__ float xh[64*120];   // [c][10 r][12 cl]
    __shared__ float wl[6912];     // 12*64*9
    const int tid = threadIdx.x;
    const int ty = blockIdx.y*8, tx = blockIdx.x*8;

    for (int idx = tid; idx < 6912; idx += 256) wl[idx] = W[idx];
    for (int idx = tid; idx < 1600; idx += 256) {
        int g = idx/400, rem = idx%400;
        int p100 = rem>>2, q = rem&3;
        int r = p100/10, cl = p100%10;
        float4 v = *(const float4*)(x + (size_t)g*GP
                     + ((size_t)(ty + r + 3)*SP + tx + cl + 3)*16 + q*4);
        int c0 = g*16 + q*4;
        xh[(c0+0)*120 + r*12 + cl] = v.x;
        xh[(c0+1)*120 + r*12 + cl] = v.y;
        xh[(c0+2)*120 + r*12 + cl] = v.z;
        xh[(c0+3)*120 + r*12 + cl] = v.w;
    }
    __syncthreads();

    const int wave = __builtin_amdgcn_readfirstlane(tid >> 6);
    const int lane = tid & 63;
    const int s = lane >> 2, cq = lane & 3;
    const int sr = s >> 1, pc0 = (s & 1)*4;
    float acc[3][4] = {};

    for (int c = cq*16; c < cq*16 + 16; ++c) {
        #pragma unroll
        for (int ky = 0; ky < 3; ++ky) {
            const float* xb = &xh[c*120 + (sr + ky)*12 + pc0];
            float4 xa = *(const float4*)xb;
            float2 xm = *(const float2*)(xb + 4);
            float xr[6] = {xa.x, xa.y, xa.z, xa.w, xm.x, xm.y};
            #pragma unroll
            for (int oj = 0; oj < 3; ++oj) {
                const float* wp = &wl[((wave*3 + oj)*64 + c)*9 + ky*3];
                #pragma unroll
                for (int kx = 0; kx < 3; ++kx) {
                    float wv = wp[kx];
                    #pragma unroll
                    for (int q = 0; q < 4; ++q)
                        acc[oj][q] += wv * xr[kx + q];
                }
            }
        }
    }

    #pragma unroll
    for (int oj = 0; oj < 3; ++oj)
        #pragma unroll
        for (int q = 0; q < 4; ++q) {
            float v = acc[oj][q];
            v += __shfl_xor(v, 1, 64);
            v += __shfl_xor(v, 2, 64);
            acc[oj][q] = v;
        }

    if (cq == 0) {
        #pragma unroll
        for (int oj = 0; oj < 3; ++oj) {
            int o = wave*3 + oj;
            float bo = b[o];
            int c3 = o >> 2, r = (o >> 1) & 1, s2 = o & 1;
            int h = ty + sr;
            #pragma unroll
            for (int q = 0; q < 4; ++q) {
                int w = tx + pc0 + q;
                out[c3*65536 + (2*h + r)*256 + 2*w + s2] = acc[oj][q] + bo;
            }
        }
    }
}

// ---------------------------------------------------------------------------
extern "C" void kernel_launch(void* const* d_in, const int* in_sizes, int n_in,
                              void* d_out, int out_size, void* d_ws, size_t ws_size,
                              hipStream_t stream) {
    const float* inf   = (const float*)d_in[0];
    const float* cinw  = (const float*)d_in[1];
    const float* cinb  = (const float*)d_in[2];
    const float* redw  = (const float*)d_in[3];
    const float* gam   = (const float*)d_in[4];
    const float* bet   = (const float*)d_in[5];
    const float* spw   = (const float*)d_in[6];
    const float* spb   = (const float*)d_in[7];
    const float* cow   = (const float*)d_in[8];
    const float* cob   = (const float*)d_in[9];

    float* ws = (float*)d_ws;
    float* x0 = ws;
    float* x1 = ws + XBUF2;
    float* tA = ws + OFF_TA;
    float* tB = ws + OFF_TB;

    conv_in_kernel<<<dim3(80, 4), 256, 0, stream>>>(
        inf, cinw, cinb, x0, x1, tA, redw);

    float* cur = x0; float* nxt = x1;
    for (int l = 0; l < 6; ++l) {
        const int doNext = (l < 5);
        float* tread  = (l & 1) ? tB : tA;
        float* twrite = (l & 1) ? tA : tB;
        e_kernel<<<1184, 256, 0, stream>>>(
            cur, tread, twrite,
            gam + l*16, bet + l*16,
            spw + l*3136, spb + l*196,
            redw + (doNext ? (l+1)*1024 : 0),
            nxt, doNext);
        float* t = cur; cur = nxt; nxt = t;
    }

    conv_out_ps_kernel<<<dim3(16, 16), 256, 0, stream>>>(
        cur, cow, cob, (float*)d_out);
}